// Round 8
// baseline (133.519 us; speedup 1.0000x reference)
//
#include <hip/hip_runtime.h>
#include <math.h>

#define DEVI __device__ __forceinline__

static constexpr float KD[10] = {
  0.027333068345077982f,  0.029519490925774643f, -0.039134249302383094f,
  0.1993975339773936f,    0.7234076904024206f,    0.6339789634582119f,
  0.01660210576452232f,  -0.17532808990845047f,  -0.021101834024758855f,
  0.019538882735286728f};

// ---------- workspace layout (float offsets) ----------
#define CE_OFF     0         // 105000 floats (ce per pixel, 0 for non-negatives)
#define ACC_OFF    105000    // 3 x 8 floats
#define SUMGT_OFF  105024    // 3 floats
#define CCNT_OFF   105027    // 3 uints
#define STATE_OFF  105030    // 3 x 8 words: [0]=ibin [1]=rem [2]=kf(float) [3]=k_take
#define PH_OFF     105056    // per-scale 8-bit hist partials: NBs x 256 uints each
#define PH1_REL    80128     // NB3*256
#define PH2_REL    100352    // + NB4*256
#define CBUF_OFF   210528    // 3 x CAP floats
#define CAP        49152
#define PART_OFF   357984    // 3 x PART_STRIDE floats (per-block partials)
#define PART_STRIDE 3840     // >= 2*NB3*6

#define NB3 313
#define NB4 79
#define NB5 20

// tiny: zero acc/sumgt/ccnt/state + out (global hist is gone -> nothing big to clear)
__global__ void zero_kernel(float* __restrict__ ws, float* __restrict__ out) {
  int t = threadIdx.x;
  if (t < 64) ws[ACC_OFF + t] = 0.f;
  if (t < 3) out[t] = 0.f;
}

// waverec3 on a 20-vector + offset, accumulating smooth_l1 over the 100 outputs.
// FULLY STREAMING: all three IDWT stages via 5-wide rolling windows (no arrays).
DEVI float recon_sl1(const float* c, float off) {
  float a1w0 = 0.f, a1w1 = 0.f, a1w2 = 0.f, a1w3 = 0.f, a1w4 = 0.f;
  float a2w0 = 0.f, a2w1 = 0.f, a2w2 = 0.f, a2w3 = 0.f, a2w4 = 0.f;
  float acc = 0.f;
#pragma unroll
  for (int j1 = 0; j1 < 31; ++j1) {
    int b = j1 >> 1;
    float a1v;
    if (j1 & 1)
      a1v = KD[0]*c[b] + KD[2]*c[b+1] + KD[4]*c[b+2] + KD[6]*c[b+3] + KD[8]*c[b+4];
    else
      a1v = KD[1]*c[b] + KD[3]*c[b+1] + KD[5]*c[b+2] + KD[7]*c[b+3] + KD[9]*c[b+4];
    a1w0 = a1w1; a1w1 = a1w2; a1w2 = a1w3; a1w3 = a1w4; a1w4 = a1v;
    if (j1 >= 4) {
#pragma unroll
      for (int t = 0; t < 2; ++t) {
        float a2v;
        if (t)
          a2v = KD[0]*a1w0 + KD[2]*a1w1 + KD[4]*a1w2 + KD[6]*a1w3 + KD[8]*a1w4;
        else
          a2v = KD[1]*a1w0 + KD[3]*a1w1 + KD[5]*a1w2 + KD[7]*a1w3 + KD[9]*a1w4;
        a2w0 = a2w1; a2w1 = a2w2; a2w2 = a2w3; a2w3 = a2w4; a2w4 = a2v;
        int j2 = 2 * (j1 - 4) + t;
        if (j2 >= 4) {
          float ve = KD[1]*a2w0 + KD[3]*a2w1 + KD[5]*a2w2 + KD[7]*a2w3 + KD[9]*a2w4 + off;
          float vo = KD[0]*a2w0 + KD[2]*a2w1 + KD[4]*a2w2 + KD[6]*a2w3 + KD[8]*a2w4 + off;
          float ae = fabsf(ve);
          acc += (ae < 1.f) ? 0.5f * ve * ve : ae - 0.5f;
          float ao = fabsf(vo);
          acc += (ao < 1.f) ? 0.5f * vo * vo : ao - 0.5f;
        }
      }
    }
  }
  return acc;
}

DEVI float wave_sum(float v) {
#pragma unroll
  for (int d = 32; d; d >>= 1) v += __shfl_down(v, d);
  return v;
}

DEVI float block_sum(float v, float* sh) {
  int lane = threadIdx.x & 63, wid = threadIdx.x >> 6;
  v = wave_sum(v);
  if (lane == 0) sh[wid] = v;
  __syncthreads();
  if (threadIdx.x == 0) {
    float s = 0.f;
    int nw = blockDim.x >> 6;
    for (int w = 0; w < nw; ++w) s += sh[w];
    sh[0] = s;
  }
  __syncthreads();
  float r = sh[0];
  __syncthreads();
  return r;
}

// inclusive suffix sum across 256 threads; sh must be int[256]
DEVI int suffix_scan_256(int v, int* sh) {
  int t = threadIdx.x;
  sh[t] = v;
  __syncthreads();
#pragma unroll
  for (int off = 1; off < 256; off <<= 1) {
    int x = (t + off < 256) ? sh[t + off] : 0;
    __syncthreads();
    sh[t] += x;
    __syncthreads();
  }
  return sh[t];
}

// Fused over 3 scales; 256-thread blocks; per-block LDS 8-bit CE histogram
// flushed as NON-ATOMIC per-block partials (kills global atomic contention).
// partials per block slot: [0]=cnt_pos [1]=cnt_neg [2]=sum_ce_pos
// [3]=sum_tcl_ttm [4]=sum_tcl_negm [5]=sum_ttm_pp
// blockIdx.y = axis (0: x-contour + all CE/mask/hist work; 1: y-contour only)
__global__ void __launch_bounds__(256, 2)
pixel_kernel(const float* __restrict__ cls3, const float* __restrict__ reg3, const float* __restrict__ gt3,
             const float* __restrict__ cls4, const float* __restrict__ reg4, const float* __restrict__ gt4,
             const float* __restrict__ cls5, const float* __restrict__ reg5, const float* __restrict__ gt5,
             float* __restrict__ ws) {
  int bx = blockIdx.x, axis = blockIdx.y;
  const float *cls, *reg, *gt;
  int M, HW, ceOff, partBase, phRel, nb, lbx;
  if (bx < NB3) {
    cls = cls3; reg = reg3; gt = gt3; M = 80000; HW = 10000;
    ceOff = 0; partBase = PART_OFF; phRel = 0; nb = NB3; lbx = bx;
  } else if (bx < NB3 + NB4) {
    cls = cls4; reg = reg4; gt = gt4; M = 20000; HW = 2500;
    ceOff = 80000; partBase = PART_OFF + PART_STRIDE; phRel = PH1_REL; nb = NB4; lbx = bx - NB3;
  } else {
    cls = cls5; reg = reg5; gt = gt5; M = 5000; HW = 625;
    ceOff = 100000; partBase = PART_OFF + 2 * PART_STRIDE; phRel = PH2_REL; nb = NB5; lbx = bx - NB3 - NB4;
  }
  float* ceArr = ws + ceOff;
  unsigned* ph = (unsigned*)(ws + PH_OFF) + phRel;

  __shared__ unsigned hlds[256];
  __shared__ float shp[4][6];
  hlds[threadIdx.x] = 0u;
  __syncthreads();

  int p = lbx * 256 + threadIdx.x;
  float cnt_pos = 0.f, cnt_neg = 0.f, s_ce_pos = 0.f, s_tcl_ttm = 0.f, s_tcl_negm = 0.f;
  float s_ttm_pp = 0.f;
  if (p < M) {
    int n = p / HW, hw = p % HW;
    const float* gb = gt  + (size_t)n * 45 * HW + hw;
    const float* rb = reg + (size_t)n * 42 * HW + hw;
    float tr = gb[0], train = gb[2*(size_t)HW];
    float ttm = tr * train;

    if (axis == 0) {
      const float* cb = cls + (size_t)n * 4 * HW + hw;
      float l0 = cb[0], l1 = cb[(size_t)HW], l2 = cb[2*(size_t)HW], l3 = cb[3*(size_t)HW];
      float tcl = gb[(size_t)HW];

      float m1 = fmaxf(l0, l1);
      float lse1 = m1 + __logf(__expf(l0 - m1) + __expf(l1 - m1));
      float ce_tr = lse1 - ((tr > 0.5f) ? l1 : l0);
      float m2 = fmaxf(l2, l3);
      float lse2 = m2 + __logf(__expf(l2 - m2) + __expf(l3 - m2));
      float ce_tcl = lse2 - ((tcl > 0.5f) ? l3 : l2);

      bool pos = ttm > 0.f;
      bool neg = ((1.f - tr) * train) > 0.f;
      float cev = neg ? ce_tr : 0.f;
      ceArr[p] = cev;
      if (neg) atomicAdd(&hlds[__float_as_uint(cev) >> 23], 1u);  // LDS-local

      cnt_pos = pos ? 1.f : 0.f;
      cnt_neg = neg ? 1.f : 0.f;
      s_ce_pos = pos ? ce_tr : 0.f;
      s_tcl_ttm = ce_tcl * ttm;
      s_tcl_negm = ce_tcl * (1.f - ttm);
    }

    // contour (this axis): linearity => reconstruct the coefficient difference
    int rc0 = (axis == 0) ? 0 : 21;
    int gc0 = (axis == 0) ? 3 : 24;
    float d[20];
#pragma unroll
    for (int c = 0; c < 20; ++c) d[c] = rb[(size_t)(rc0 + c) * HW] - gb[(size_t)(gc0 + c) * HW];
    float dc = rb[(size_t)(rc0 + 20) * HW] - gb[(size_t)(gc0 + 20) * HW];
    s_ttm_pp = ttm * recon_sl1(d, dc);
  }

  int lane = threadIdx.x & 63, wid = threadIdx.x >> 6;
  cnt_pos = wave_sum(cnt_pos);
  cnt_neg = wave_sum(cnt_neg);
  s_ce_pos = wave_sum(s_ce_pos);
  s_tcl_ttm = wave_sum(s_tcl_ttm);
  s_tcl_negm = wave_sum(s_tcl_negm);
  s_ttm_pp = wave_sum(s_ttm_pp);
  if (lane == 0) {
    shp[wid][0] = cnt_pos; shp[wid][1] = cnt_neg; shp[wid][2] = s_ce_pos;
    shp[wid][3] = s_tcl_ttm; shp[wid][4] = s_tcl_negm; shp[wid][5] = s_ttm_pp;
  }
  __syncthreads();   // covers hist atomics + shp
  if (threadIdx.x < 6) {
    float s = shp[0][threadIdx.x] + shp[1][threadIdx.x] + shp[2][threadIdx.x] + shp[3][threadIdx.x];
    ws[partBase + (size_t)(axis * nb + lbx) * 6 + threadIdx.x] = s;
  }
  if (axis == 0)
    ph[(size_t)lbx * 256 + threadIdx.x] = hlds[threadIdx.x];  // coalesced, no atomics
}

// one block per scale: reduce partials -> acc; column-sum hist partials;
// suffix-scan 256 exponent bins for the k-th largest negative CE
__global__ void select_bin_kernel(float* __restrict__ ws) {
  int s = blockIdx.x, t = threadIdx.x;
  float* acc = ws + ACC_OFF + s * 8;
  int* st = (int*)(ws + STATE_OFF) + s * 8;
  int phRel = (s == 0) ? 0 : (s == 1 ? PH1_REL : PH2_REL);
  const unsigned* ph = (const unsigned*)(ws + PH_OFF) + phRel;
  const float* part = ws + PART_OFF + s * PART_STRIDE;
  int nb0 = (s == 0) ? NB3 : (s == 1 ? NB4 : NB5);
  int npart = 2 * nb0;

  __shared__ int sh[256];
  __shared__ int sel[2];
  __shared__ float red[4];

  float a0 = 0.f, a1 = 0.f, a2 = 0.f, a3 = 0.f, a4 = 0.f, a5 = 0.f;
  for (int i = t; i < npart; i += 256) {
    const float* p6 = part + (size_t)i * 6;
    a0 += p6[0]; a1 += p6[1]; a2 += p6[2]; a3 += p6[3]; a4 += p6[4]; a5 += p6[5];
  }
  a0 = block_sum(a0, red);
  a1 = block_sum(a1, red);
  a2 = block_sum(a2, red);
  a3 = block_sum(a3, red);
  a4 = block_sum(a4, red);
  a5 = block_sum(a5, red);
  if (t == 0) { acc[0] = a0; acc[1] = a1; acc[2] = a2; acc[3] = a3; acc[4] = a4; acc[5] = a5; }

  float cnt_pos = a0, cnt_negf = a1;
  int cnt_neg = (int)cnt_negf;
  float kf = (cnt_pos > 0.f) ? fminf(cnt_negf, floorf(3.f * cnt_pos)) : 100.f;
  int k_take = min((int)kf, cnt_neg);

  int ibin, rem;
  if (k_take >= cnt_neg) { ibin = -1; rem = 0; }        // take all negatives
  else if (k_take <= 0)  { ibin = 256; rem = 0; }       // take none
  else {
    int h = 0;
    for (int i = 0; i < nb0; ++i) h += (int)ph[(size_t)i * 256 + t];  // coalesced column sum
    int suf = suffix_scan_256(h, sh);
    int above = suf - h;
    if (suf >= k_take && above < k_take) { sel[0] = t; sel[1] = k_take - above; }
    __syncthreads();
    ibin = sel[0]; rem = sel[1];
  }
  if (t == 0) {
    st[0] = ibin;
    st[1] = rem;
    ((float*)st)[2] = kf;
    st[3] = k_take;
  }
}

// grid-wide, two-phase: (A) sum ce strictly above bin + count in-bin, ONE
// reservation atomic per block; (B) rank-write in-bin values to cbuf.
__global__ void compact_kernel(float* __restrict__ ws) {
  int s = blockIdx.y;
  int M   = (s == 0) ? 80000 : (s == 1 ? 20000 : 5000);
  int off = (s == 0) ? 0     : (s == 1 ? 80000 : 100000);
  const int* st = (const int*)(ws + STATE_OFF) + s * 8;
  int ibin = st[0];
  __shared__ float red[4];
  __shared__ unsigned sbase;
  __shared__ unsigned wcnt;
  if (ibin >= 256) return;  // take-none: nothing to do (all blocks uniform)

  const float* ce = ws + off;
  float* cbuf = ws + CBUF_OFF + s * CAP;
  unsigned* ccnt = (unsigned*)(ws + CCNT_OFF) + s;
  int stride = gridDim.x * blockDim.x;
  int i0 = blockIdx.x * blockDim.x + threadIdx.x;

  float sum = 0.f;
  float cin = 0.f;
  for (int i = i0; i < M; i += stride) {
    float v = ce[i];
    int bin = (int)(__float_as_uint(v) >> 23);
    if (bin > ibin) sum += v;
    else if (bin == ibin) cin += 1.f;
  }
  sum = block_sum(sum, red);
  cin = block_sum(cin, red);
  if (threadIdx.x == 0) {
    if (sum != 0.f) atomicAdd(ws + SUMGT_OFF + s, sum);
    sbase = (cin > 0.f) ? atomicAdd(ccnt, (unsigned)cin) : 0u;
    wcnt = 0u;
  }
  __syncthreads();
  if (ibin < 0) return;  // take-all: no in-bin phase
  unsigned base = sbase;
  for (int i = i0; i < M; i += stride) {
    float v = ce[i];
    if ((int)(__float_as_uint(v) >> 23) == ibin) {
      unsigned idx = base + atomicAdd(&wcnt, 1u);
      if (idx < CAP) cbuf[idx] = v;
    }
  }
}

// one block per scale: 3 radix passes (mantissa bits 22..15, 14..7, 6..0) over
// the compacted in-bin values -> exact k-th value; tie-corrected sum; losses.
__global__ void final_kernel(float* __restrict__ ws, float* __restrict__ out) {
  int s = blockIdx.x, t = threadIdx.x;
  int M = (s == 0) ? 80000 : (s == 1 ? 20000 : 5000);
  const float* acc = ws + ACC_OFF + s * 8;
  const int* st = (const int*)(ws + STATE_OFF) + s * 8;

  __shared__ int hist[256];
  __shared__ int sh[256];
  __shared__ int sel[2];
  __shared__ float red[8];

  float cnt_pos = acc[0];
  float s_ce_pos = acc[2], s_tcl_ttm = acc[3], s_tcl_negm = acc[4], s_ttm_pp = acc[5];
  int ibin = st[0], rem = st[1];
  float kf = ((const float*)st)[2];
  float loss_neg = ws[SUMGT_OFF + s];

  if (rem > 0) {
    int cnt = min((int)((unsigned*)(ws + CCNT_OFF))[s], CAP);
    const float* cbuf = ws + CBUF_OFF + s * CAP;

    unsigned prefix = (unsigned)ibin << 23;
    int remcur = rem;
    const int shifts[3] = {15, 7, 0};
    const int widths[3] = {8, 8, 7};
#pragma unroll
    for (int pass = 0; pass < 3; ++pass) {
      int sft = shifts[pass], w = widths[pass];
      unsigned msk = (1u << w) - 1u;
      hist[t] = 0; __syncthreads();
      for (int i = t; i < cnt; i += 256) {
        unsigned b = __float_as_uint(cbuf[i]);
        if (((b ^ prefix) >> (sft + w)) == 0u) atomicAdd(&hist[(b >> sft) & msk], 1);
      }
      __syncthreads();
      int h = hist[t];
      int suf = suffix_scan_256(h, sh);
      int above = suf - h;
      if (suf >= remcur && above < remcur) { sel[0] = t; sel[1] = remcur - above; }
      __syncthreads();
      prefix |= (unsigned)sel[0] << sft;
      remcur = sel[1];
      __syncthreads();
    }

    float tval = __uint_as_float(prefix);
    float sum_in = 0.f, cgt = 0.f;
    for (int i = t; i < cnt; i += 256) {
      unsigned b = __float_as_uint(cbuf[i]);
      if (b > prefix) { sum_in += cbuf[i]; cgt += 1.f; }
    }
    sum_in = block_sum(sum_in, red);
    cgt = block_sum(cgt, red);
    loss_neg += sum_in + ((float)rem - cgt) * tval;
  }

  if (t == 0) {
    float n_pos = cnt_pos;
    float loss_pos = (n_pos > 0.f) ? s_ce_pos : 0.f;
    float loss_tr = (loss_pos + loss_neg) / (n_pos + kf);

    float negm = (float)M - n_pos;
    float mp = s_tcl_ttm / fmaxf(n_pos, 1.f);
    float mn = s_tcl_negm / fmaxf(negm, 1.f);
    float loss_tcl = (n_pos > 0.f) ? (mp + 0.5f * mn) : 0.f;

    float loss_ct = (n_pos > 0.f) ? (0.5f * s_ttm_pp / (n_pos * 200.f)) : 0.f;

    atomicAdd(&out[0], loss_tr);
    atomicAdd(&out[1], loss_tcl);
    atomicAdd(&out[2], loss_ct);
  }
}

extern "C" void kernel_launch(void* const* d_in, const int* in_sizes, int n_in,
                              void* d_out, int out_size, void* d_ws, size_t ws_size,
                              hipStream_t stream) {
  (void)in_sizes; (void)n_in; (void)out_size; (void)ws_size;
  const float* cls3 = (const float*)d_in[0];
  const float* reg3 = (const float*)d_in[1];
  const float* gt3  = (const float*)d_in[2];
  const float* cls4 = (const float*)d_in[3];
  const float* reg4 = (const float*)d_in[4];
  const float* gt4  = (const float*)d_in[5];
  const float* cls5 = (const float*)d_in[6];
  const float* reg5 = (const float*)d_in[7];
  const float* gt5  = (const float*)d_in[8];

  float* ws = (float*)d_ws;
  float* out = (float*)d_out;

  zero_kernel<<<1, 64, 0, stream>>>(ws, out);

  pixel_kernel<<<dim3(NB3 + NB4 + NB5, 2), 256, 0, stream>>>(
      cls3, reg3, gt3, cls4, reg4, gt4, cls5, reg5, gt5, ws);

  select_bin_kernel<<<3, 256, 0, stream>>>(ws);
  compact_kernel<<<dim3(96, 3), 256, 0, stream>>>(ws);
  final_kernel<<<3, 256, 0, stream>>>(ws, out);
}

// Round 9
// 98.966 us; speedup vs baseline: 1.3491x; 1.3491x over previous
//
#include <hip/hip_runtime.h>
#include <math.h>

#define DEVI __device__ __forceinline__

static constexpr float KD[10] = {
  0.027333068345077982f,  0.029519490925774643f, -0.039134249302383094f,
  0.1993975339773936f,    0.7234076904024206f,    0.6339789634582119f,
  0.01660210576452232f,  -0.17532808990845047f,  -0.021101834024758855f,
  0.019538882735286728f};

// ---------- workspace layout (float offsets) ----------
#define CE_OFF     0         // 105000 floats (ce per pixel, 0 for non-negatives)
#define ACC_OFF    105000    // 3 x 8 floats
#define SUMGT_OFF  105024    // 3 floats
#define CCNT_OFF   105027    // 3 uints
#define STATE_OFF  105030    // 3 x 8 words: [0]=ibin [1]=rem [2]=kf [3]=k_take [4]=jbin [5]=rem2
#define PH_OFF     105056    // exp-hist partials: NBs x 256 uints per scale
#define PH1_REL    80128     // NB3*256
#define PH2_REL    100352    // + NB4*256
#define MH_OFF     210528    // m8-hist partials: 3 x 96 x 256 uints
#define MH_STRIDE  24576
#define CBUF_OFF   284256    // 3 x CAP floats
#define CAP        61440
#define PART_OFF   468576    // 3 x PART_STRIDE floats (per-block partials)
#define PART_STRIDE 3840

#define NB3 313
#define NB4 79
#define NB5 20
#define NBR 96               // refine/compact grid.x

// tiny: zero acc/sumgt/ccnt/state + out
__global__ void zero_kernel(float* __restrict__ ws, float* __restrict__ out) {
  int t = threadIdx.x;
  if (t < 64) ws[ACC_OFF + t] = 0.f;
  if (t < 3) out[t] = 0.f;
}

// waverec3 on a 20-vector + offset, accumulating smooth_l1 over the 100 outputs.
// FULLY STREAMING: all three IDWT stages via 5-wide rolling windows (no arrays).
DEVI float recon_sl1(const float* c, float off) {
  float a1w0 = 0.f, a1w1 = 0.f, a1w2 = 0.f, a1w3 = 0.f, a1w4 = 0.f;
  float a2w0 = 0.f, a2w1 = 0.f, a2w2 = 0.f, a2w3 = 0.f, a2w4 = 0.f;
  float acc = 0.f;
#pragma unroll
  for (int j1 = 0; j1 < 31; ++j1) {
    int b = j1 >> 1;
    float a1v;
    if (j1 & 1)
      a1v = KD[0]*c[b] + KD[2]*c[b+1] + KD[4]*c[b+2] + KD[6]*c[b+3] + KD[8]*c[b+4];
    else
      a1v = KD[1]*c[b] + KD[3]*c[b+1] + KD[5]*c[b+2] + KD[7]*c[b+3] + KD[9]*c[b+4];
    a1w0 = a1w1; a1w1 = a1w2; a1w2 = a1w3; a1w3 = a1w4; a1w4 = a1v;
    if (j1 >= 4) {
#pragma unroll
      for (int t = 0; t < 2; ++t) {
        float a2v;
        if (t)
          a2v = KD[0]*a1w0 + KD[2]*a1w1 + KD[4]*a1w2 + KD[6]*a1w3 + KD[8]*a1w4;
        else
          a2v = KD[1]*a1w0 + KD[3]*a1w1 + KD[5]*a1w2 + KD[7]*a1w3 + KD[9]*a1w4;
        a2w0 = a2w1; a2w1 = a2w2; a2w2 = a2w3; a2w3 = a2w4; a2w4 = a2v;
        int j2 = 2 * (j1 - 4) + t;
        if (j2 >= 4) {
          float ve = KD[1]*a2w0 + KD[3]*a2w1 + KD[5]*a2w2 + KD[7]*a2w3 + KD[9]*a2w4 + off;
          float vo = KD[0]*a2w0 + KD[2]*a2w1 + KD[4]*a2w2 + KD[6]*a2w3 + KD[8]*a2w4 + off;
          float ae = fabsf(ve);
          acc += (ae < 1.f) ? 0.5f * ve * ve : ae - 0.5f;
          float ao = fabsf(vo);
          acc += (ao < 1.f) ? 0.5f * vo * vo : ao - 0.5f;
        }
      }
    }
  }
  return acc;
}

DEVI float wave_sum(float v) {
#pragma unroll
  for (int d = 32; d; d >>= 1) v += __shfl_down(v, d);
  return v;
}

DEVI float block_sum(float v, float* sh) {
  int lane = threadIdx.x & 63, wid = threadIdx.x >> 6;
  v = wave_sum(v);
  if (lane == 0) sh[wid] = v;
  __syncthreads();
  if (threadIdx.x == 0) {
    float s = 0.f;
    int nw = blockDim.x >> 6;
    for (int w = 0; w < nw; ++w) s += sh[w];
    sh[0] = s;
  }
  __syncthreads();
  float r = sh[0];
  __syncthreads();
  return r;
}

// inclusive suffix sum across 256 threads; sh must be int[256]
DEVI int suffix_scan_256(int v, int* sh) {
  int t = threadIdx.x;
  sh[t] = v;
  __syncthreads();
#pragma unroll
  for (int off = 1; off < 256; off <<= 1) {
    int x = (t + off < 256) ? sh[t + off] : 0;
    __syncthreads();
    sh[t] += x;
    __syncthreads();
  }
  return sh[t];
}

// Fused over 3 scales; per-block LDS 8-bit-exp CE histogram flushed as
// NON-ATOMIC per-block partials. blockIdx.y = axis.
__global__ void __launch_bounds__(256, 2)
pixel_kernel(const float* __restrict__ cls3, const float* __restrict__ reg3, const float* __restrict__ gt3,
             const float* __restrict__ cls4, const float* __restrict__ reg4, const float* __restrict__ gt4,
             const float* __restrict__ cls5, const float* __restrict__ reg5, const float* __restrict__ gt5,
             float* __restrict__ ws) {
  int bx = blockIdx.x, axis = blockIdx.y;
  const float *cls, *reg, *gt;
  int M, HW, ceOff, partBase, phRel, nb, lbx;
  if (bx < NB3) {
    cls = cls3; reg = reg3; gt = gt3; M = 80000; HW = 10000;
    ceOff = 0; partBase = PART_OFF; phRel = 0; nb = NB3; lbx = bx;
  } else if (bx < NB3 + NB4) {
    cls = cls4; reg = reg4; gt = gt4; M = 20000; HW = 2500;
    ceOff = 80000; partBase = PART_OFF + PART_STRIDE; phRel = PH1_REL; nb = NB4; lbx = bx - NB3;
  } else {
    cls = cls5; reg = reg5; gt = gt5; M = 5000; HW = 625;
    ceOff = 100000; partBase = PART_OFF + 2 * PART_STRIDE; phRel = PH2_REL; nb = NB5; lbx = bx - NB3 - NB4;
  }
  float* ceArr = ws + ceOff;
  unsigned* ph = (unsigned*)(ws + PH_OFF) + phRel;

  __shared__ unsigned hlds[256];
  __shared__ float shp[4][6];
  hlds[threadIdx.x] = 0u;
  __syncthreads();

  int p = lbx * 256 + threadIdx.x;
  float cnt_pos = 0.f, cnt_neg = 0.f, s_ce_pos = 0.f, s_tcl_ttm = 0.f, s_tcl_negm = 0.f;
  float s_ttm_pp = 0.f;
  if (p < M) {
    int n = p / HW, hw = p % HW;
    const float* gb = gt  + (size_t)n * 45 * HW + hw;
    const float* rb = reg + (size_t)n * 42 * HW + hw;
    float tr = gb[0], train = gb[2*(size_t)HW];
    float ttm = tr * train;

    if (axis == 0) {
      const float* cb = cls + (size_t)n * 4 * HW + hw;
      float l0 = cb[0], l1 = cb[(size_t)HW], l2 = cb[2*(size_t)HW], l3 = cb[3*(size_t)HW];
      float tcl = gb[(size_t)HW];

      float m1 = fmaxf(l0, l1);
      float lse1 = m1 + __logf(__expf(l0 - m1) + __expf(l1 - m1));
      float ce_tr = lse1 - ((tr > 0.5f) ? l1 : l0);
      float m2 = fmaxf(l2, l3);
      float lse2 = m2 + __logf(__expf(l2 - m2) + __expf(l3 - m2));
      float ce_tcl = lse2 - ((tcl > 0.5f) ? l3 : l2);

      bool pos = ttm > 0.f;
      bool neg = ((1.f - tr) * train) > 0.f;
      float cev = neg ? ce_tr : 0.f;
      ceArr[p] = cev;
      if (neg) atomicAdd(&hlds[__float_as_uint(cev) >> 23], 1u);  // LDS-local

      cnt_pos = pos ? 1.f : 0.f;
      cnt_neg = neg ? 1.f : 0.f;
      s_ce_pos = pos ? ce_tr : 0.f;
      s_tcl_ttm = ce_tcl * ttm;
      s_tcl_negm = ce_tcl * (1.f - ttm);
    }

    int rc0 = (axis == 0) ? 0 : 21;
    int gc0 = (axis == 0) ? 3 : 24;
    float d[20];
#pragma unroll
    for (int c = 0; c < 20; ++c) d[c] = rb[(size_t)(rc0 + c) * HW] - gb[(size_t)(gc0 + c) * HW];
    float dc = rb[(size_t)(rc0 + 20) * HW] - gb[(size_t)(gc0 + 20) * HW];
    s_ttm_pp = ttm * recon_sl1(d, dc);
  }

  int lane = threadIdx.x & 63, wid = threadIdx.x >> 6;
  cnt_pos = wave_sum(cnt_pos);
  cnt_neg = wave_sum(cnt_neg);
  s_ce_pos = wave_sum(s_ce_pos);
  s_tcl_ttm = wave_sum(s_tcl_ttm);
  s_tcl_negm = wave_sum(s_tcl_negm);
  s_ttm_pp = wave_sum(s_ttm_pp);
  if (lane == 0) {
    shp[wid][0] = cnt_pos; shp[wid][1] = cnt_neg; shp[wid][2] = s_ce_pos;
    shp[wid][3] = s_tcl_ttm; shp[wid][4] = s_tcl_negm; shp[wid][5] = s_ttm_pp;
  }
  __syncthreads();
  if (threadIdx.x < 6) {
    float s = shp[0][threadIdx.x] + shp[1][threadIdx.x] + shp[2][threadIdx.x] + shp[3][threadIdx.x];
    ws[partBase + (size_t)(axis * nb + lbx) * 6 + threadIdx.x] = s;
  }
  if (axis == 0)
    ph[(size_t)lbx * 256 + threadIdx.x] = hlds[threadIdx.x];
}

// one block per scale: reduce partials -> acc; exp-bin select -> (ibin, rem)
__global__ void selA_kernel(float* __restrict__ ws) {
  int s = blockIdx.x, t = threadIdx.x;
  float* acc = ws + ACC_OFF + s * 8;
  int* st = (int*)(ws + STATE_OFF) + s * 8;
  int phRel = (s == 0) ? 0 : (s == 1 ? PH1_REL : PH2_REL);
  const unsigned* ph = (const unsigned*)(ws + PH_OFF) + phRel;
  const float* part = ws + PART_OFF + s * PART_STRIDE;
  int nb0 = (s == 0) ? NB3 : (s == 1 ? NB4 : NB5);
  int npart = 2 * nb0;

  __shared__ int sh[256];
  __shared__ int sel[2];
  __shared__ float red[4];

  float a0 = 0.f, a1 = 0.f, a2 = 0.f, a3 = 0.f, a4 = 0.f, a5 = 0.f;
  for (int i = t; i < npart; i += 256) {
    const float* p6 = part + (size_t)i * 6;
    a0 += p6[0]; a1 += p6[1]; a2 += p6[2]; a3 += p6[3]; a4 += p6[4]; a5 += p6[5];
  }
  a0 = block_sum(a0, red);
  a1 = block_sum(a1, red);
  a2 = block_sum(a2, red);
  a3 = block_sum(a3, red);
  a4 = block_sum(a4, red);
  a5 = block_sum(a5, red);
  if (t == 0) { acc[0] = a0; acc[1] = a1; acc[2] = a2; acc[3] = a3; acc[4] = a4; acc[5] = a5; }

  float cnt_pos = a0, cnt_negf = a1;
  int cnt_neg = (int)cnt_negf;
  float kf = (cnt_pos > 0.f) ? fminf(cnt_negf, floorf(3.f * cnt_pos)) : 100.f;
  int k_take = min((int)kf, cnt_neg);

  int ibin, rem;
  if (k_take >= cnt_neg) { ibin = -1; rem = 0; }        // take all negatives
  else if (k_take <= 0)  { ibin = 256; rem = 0; }       // take none
  else {
    int h = 0;
    for (int i = 0; i < nb0; ++i) h += (int)ph[(size_t)i * 256 + t];
    int suf = suffix_scan_256(h, sh);
    int above = suf - h;
    if (suf >= k_take && above < k_take) { sel[0] = t; sel[1] = k_take - above; }
    __syncthreads();
    ibin = sel[0]; rem = sel[1];
  }
  if (t == 0) {
    st[0] = ibin;
    st[1] = rem;
    ((float*)st)[2] = kf;
    st[3] = k_take;
  }
}

// grid-wide: sum ce with exp-bin > ibin into SUMGT (1 atomic/block);
// LDS hist of mantissa[22:15] for exp-bin == ibin -> per-block partials
__global__ void refine_kernel(float* __restrict__ ws) {
  int s = blockIdx.y;
  int M   = (s == 0) ? 80000 : (s == 1 ? 20000 : 5000);
  int off = (s == 0) ? 0     : (s == 1 ? 80000 : 100000);
  const int* st = (const int*)(ws + STATE_OFF) + s * 8;
  int ibin = st[0], rem = st[1];
  if (ibin >= 256) return;   // take-none

  __shared__ unsigned hlds[256];
  __shared__ float red[4];
  hlds[threadIdx.x] = 0u;
  __syncthreads();

  const float* ce = ws + off;
  int stride = gridDim.x * blockDim.x;
  float sum = 0.f;
  for (int i = blockIdx.x * blockDim.x + threadIdx.x; i < M; i += stride) {
    float v = ce[i];
    unsigned b = __float_as_uint(v);
    int bin = (int)(b >> 23);
    if (bin > ibin) sum += v;
    else if (bin == ibin && rem > 0) atomicAdd(&hlds[(b >> 15) & 255u], 1u);
  }
  sum = block_sum(sum, red);   // syncthreads inside also orders the LDS atomics
  if (threadIdx.x == 0 && sum != 0.f) atomicAdd(ws + SUMGT_OFF + s, sum);
  if (rem > 0) {
    unsigned* mh = (unsigned*)(ws + MH_OFF) + (size_t)s * MH_STRIDE;
    mh[(size_t)blockIdx.x * 256 + threadIdx.x] = hlds[threadIdx.x];
  }
}

// one block per scale: column-sum m8 partials -> (jbin, rem2)
__global__ void selB_kernel(float* __restrict__ ws) {
  int s = blockIdx.x, t = threadIdx.x;
  int* st = (int*)(ws + STATE_OFF) + s * 8;
  int rem = st[1];

  __shared__ int sh[256];
  __shared__ int sel[2];

  int jbin = 0, rem2 = 0;
  if (rem > 0) {
    const unsigned* mh = (const unsigned*)(ws + MH_OFF) + (size_t)s * MH_STRIDE;
    int h = 0;
    for (int i = 0; i < NBR; ++i) h += (int)mh[(size_t)i * 256 + t];
    int suf = suffix_scan_256(h, sh);
    int above = suf - h;
    if (suf >= rem && above < rem) { sel[0] = t; sel[1] = rem - above; }
    __syncthreads();
    jbin = sel[0]; rem2 = sel[1];
  }
  if (t == 0) { st[4] = jbin; st[5] = rem2; }
}

// grid-wide: sum (exp==ibin, m8>jbin) into SUMGT; two-phase compact of
// (ibin,jbin) matches into cbuf
__global__ void compact_kernel(float* __restrict__ ws) {
  int s = blockIdx.y;
  int M   = (s == 0) ? 80000 : (s == 1 ? 20000 : 5000);
  int off = (s == 0) ? 0     : (s == 1 ? 80000 : 100000);
  const int* st = (const int*)(ws + STATE_OFF) + s * 8;
  int ibin = st[0], rem = st[1], jbin = st[4];
  if (rem <= 0) return;

  __shared__ float red[4];
  __shared__ unsigned sbase;
  __shared__ unsigned wcnt;

  const float* ce = ws + off;
  float* cbuf = ws + CBUF_OFF + s * CAP;
  unsigned* ccnt = (unsigned*)(ws + CCNT_OFF) + s;
  int stride = gridDim.x * blockDim.x;
  int i0 = blockIdx.x * blockDim.x + threadIdx.x;

  float sum = 0.f, cin = 0.f;
  for (int i = i0; i < M; i += stride) {
    unsigned b = __float_as_uint(ce[i]);
    if ((int)(b >> 23) == ibin) {
      int m8 = (int)((b >> 15) & 255u);
      if (m8 > jbin) sum += ce[i];
      else if (m8 == jbin) cin += 1.f;
    }
  }
  sum = block_sum(sum, red);
  cin = block_sum(cin, red);
  if (threadIdx.x == 0) {
    if (sum != 0.f) atomicAdd(ws + SUMGT_OFF + s, sum);
    sbase = (cin > 0.f) ? atomicAdd(ccnt, (unsigned)cin) : 0u;
    wcnt = 0u;
  }
  __syncthreads();
  unsigned base = sbase;
  for (int i = i0; i < M; i += stride) {
    float v = ce[i];
    unsigned b = __float_as_uint(v);
    if ((int)(b >> 23) == ibin && (int)((b >> 15) & 255u) == jbin) {
      unsigned idx = base + atomicAdd(&wcnt, 1u);
      if (idx < CAP) cbuf[idx] = v;
    }
  }
}

// one block per scale: 2 radix passes (bits 14..7, 6..0) over the small cbuf
// -> exact k-th value; tie-corrected sum; assemble losses.
__global__ void final_kernel(float* __restrict__ ws, float* __restrict__ out) {
  int s = blockIdx.x, t = threadIdx.x;
  int M = (s == 0) ? 80000 : (s == 1 ? 20000 : 5000);
  const float* acc = ws + ACC_OFF + s * 8;
  const int* st = (const int*)(ws + STATE_OFF) + s * 8;

  __shared__ int hist[256];
  __shared__ int sh[256];
  __shared__ int sel[2];
  __shared__ float red[8];

  float cnt_pos = acc[0];
  float s_ce_pos = acc[2], s_tcl_ttm = acc[3], s_tcl_negm = acc[4], s_ttm_pp = acc[5];
  int ibin = st[0], jbin = st[4], rem2 = st[5];
  float kf = ((const float*)st)[2];
  float loss_neg = ws[SUMGT_OFF + s];

  if (rem2 > 0) {
    int cnt = min((int)((unsigned*)(ws + CCNT_OFF))[s], CAP);
    const float* cbuf = ws + CBUF_OFF + s * CAP;
    unsigned prefix = ((unsigned)ibin << 23) | ((unsigned)jbin << 15);
    int remcur = rem2;

    // pass 1: bits 14..7 (all cbuf values share the 17-bit prefix)
    hist[t] = 0; __syncthreads();
    for (int i = t; i < cnt; i += 256)
      atomicAdd(&hist[(__float_as_uint(cbuf[i]) >> 7) & 255u], 1);
    __syncthreads();
    int h = hist[t];
    int suf = suffix_scan_256(h, sh);
    int above = suf - h;
    if (suf >= remcur && above < remcur) { sel[0] = t; sel[1] = remcur - above; }
    __syncthreads();
    int b1 = sel[0]; remcur = sel[1];
    __syncthreads();

    // pass 2: bits 6..0 among values matching b1
    hist[t] = 0; __syncthreads();
    for (int i = t; i < cnt; i += 256) {
      unsigned b = __float_as_uint(cbuf[i]);
      if (((b >> 7) & 255u) == (unsigned)b1) atomicAdd(&hist[b & 127u], 1);
    }
    __syncthreads();
    h = (t < 128) ? hist[t] : 0;
    suf = suffix_scan_256(h, sh);
    above = suf - h;
    if (t < 128 && suf >= remcur && above < remcur) { sel[0] = t; }
    __syncthreads();
    int b0 = sel[0];
    __syncthreads();

    prefix |= ((unsigned)b1 << 7) | (unsigned)b0;
    float tval = __uint_as_float(prefix);

    float sum_in = 0.f, cgt = 0.f;
    for (int i = t; i < cnt; i += 256) {
      unsigned b = __float_as_uint(cbuf[i]);
      if (b > prefix) { sum_in += cbuf[i]; cgt += 1.f; }
    }
    sum_in = block_sum(sum_in, red);
    cgt = block_sum(cgt, red);
    loss_neg += sum_in + ((float)rem2 - cgt) * tval;
  }

  if (t == 0) {
    float n_pos = cnt_pos;
    float loss_pos = (n_pos > 0.f) ? s_ce_pos : 0.f;
    float loss_tr = (loss_pos + loss_neg) / (n_pos + kf);

    float negm = (float)M - n_pos;
    float mp = s_tcl_ttm / fmaxf(n_pos, 1.f);
    float mn = s_tcl_negm / fmaxf(negm, 1.f);
    float loss_tcl = (n_pos > 0.f) ? (mp + 0.5f * mn) : 0.f;

    float loss_ct = (n_pos > 0.f) ? (0.5f * s_ttm_pp / (n_pos * 200.f)) : 0.f;

    atomicAdd(&out[0], loss_tr);
    atomicAdd(&out[1], loss_tcl);
    atomicAdd(&out[2], loss_ct);
  }
}

extern "C" void kernel_launch(void* const* d_in, const int* in_sizes, int n_in,
                              void* d_out, int out_size, void* d_ws, size_t ws_size,
                              hipStream_t stream) {
  (void)in_sizes; (void)n_in; (void)out_size; (void)ws_size;
  const float* cls3 = (const float*)d_in[0];
  const float* reg3 = (const float*)d_in[1];
  const float* gt3  = (const float*)d_in[2];
  const float* cls4 = (const float*)d_in[3];
  const float* reg4 = (const float*)d_in[4];
  const float* gt4  = (const float*)d_in[5];
  const float* cls5 = (const float*)d_in[6];
  const float* reg5 = (const float*)d_in[7];
  const float* gt5  = (const float*)d_in[8];

  float* ws = (float*)d_ws;
  float* out = (float*)d_out;

  zero_kernel<<<1, 64, 0, stream>>>(ws, out);

  pixel_kernel<<<dim3(NB3 + NB4 + NB5, 2), 256, 0, stream>>>(
      cls3, reg3, gt3, cls4, reg4, gt4, cls5, reg5, gt5, ws);

  selA_kernel<<<3, 256, 0, stream>>>(ws);
  refine_kernel<<<dim3(NBR, 3), 256, 0, stream>>>(ws);
  selB_kernel<<<3, 256, 0, stream>>>(ws);
  compact_kernel<<<dim3(NBR, 3), 256, 0, stream>>>(ws);
  final_kernel<<<3, 256, 0, stream>>>(ws, out);
}

// Round 10
// 79.060 us; speedup vs baseline: 1.6888x; 1.2518x over previous
//
#include <hip/hip_runtime.h>
#include <math.h>

#define DEVI __device__ __forceinline__

static constexpr float KD[10] = {
  0.027333068345077982f,  0.029519490925774643f, -0.039134249302383094f,
  0.1993975339773936f,    0.7234076904024206f,    0.6339789634582119f,
  0.01660210576452232f,  -0.17532808990845047f,  -0.021101834024758855f,
  0.019538882735286728f};

// ---------- workspace layout (float offsets) ----------
#define CE_OFF     0         // 105000 floats (ce per pixel, 0 for non-negatives)
#define ACC_OFF    105000    // 3 x 8 floats
#define SUMGT_OFF  105024    // 3 floats
#define CCNT_OFF   105027    // 3 uints
#define STATE_OFF  105030    // 3 x 8 words: [0]=ibin [1]=rem [2]=kf [3]=k_take [4]=jbin [5]=rem2
#define PH_OFF     105056    // exp-hist partials: NBs x 256 uints per scale (16B-aligned)
#define PH1_REL    80128     // NB3*256
#define PH2_REL    100352    // + NB4*256
#define MH_OFF     210528    // m8-hist partials: 3 x 96 x 256 uints
#define MH_STRIDE  24576
#define CBUF_OFF   284256    // 3 x CAP floats
#define CAP        61440
#define PART_OFF   468576    // 3 x PART_STRIDE floats (per-block partials)
#define PART_STRIDE 3840

#define NB3 313
#define NB4 79
#define NB5 20
#define NBR 96               // refine/compact grid.x

// waverec3 on a 20-vector + offset, accumulating smooth_l1 over the 100 outputs.
// FULLY STREAMING: all three IDWT stages via 5-wide rolling windows (no arrays).
DEVI float recon_sl1(const float* c, float off) {
  float a1w0 = 0.f, a1w1 = 0.f, a1w2 = 0.f, a1w3 = 0.f, a1w4 = 0.f;
  float a2w0 = 0.f, a2w1 = 0.f, a2w2 = 0.f, a2w3 = 0.f, a2w4 = 0.f;
  float acc = 0.f;
#pragma unroll
  for (int j1 = 0; j1 < 31; ++j1) {
    int b = j1 >> 1;
    float a1v;
    if (j1 & 1)
      a1v = KD[0]*c[b] + KD[2]*c[b+1] + KD[4]*c[b+2] + KD[6]*c[b+3] + KD[8]*c[b+4];
    else
      a1v = KD[1]*c[b] + KD[3]*c[b+1] + KD[5]*c[b+2] + KD[7]*c[b+3] + KD[9]*c[b+4];
    a1w0 = a1w1; a1w1 = a1w2; a1w2 = a1w3; a1w3 = a1w4; a1w4 = a1v;
    if (j1 >= 4) {
#pragma unroll
      for (int t = 0; t < 2; ++t) {
        float a2v;
        if (t)
          a2v = KD[0]*a1w0 + KD[2]*a1w1 + KD[4]*a1w2 + KD[6]*a1w3 + KD[8]*a1w4;
        else
          a2v = KD[1]*a1w0 + KD[3]*a1w1 + KD[5]*a1w2 + KD[7]*a1w3 + KD[9]*a1w4;
        a2w0 = a2w1; a2w1 = a2w2; a2w2 = a2w3; a2w3 = a2w4; a2w4 = a2v;
        int j2 = 2 * (j1 - 4) + t;
        if (j2 >= 4) {
          float ve = KD[1]*a2w0 + KD[3]*a2w1 + KD[5]*a2w2 + KD[7]*a2w3 + KD[9]*a2w4 + off;
          float vo = KD[0]*a2w0 + KD[2]*a2w1 + KD[4]*a2w2 + KD[6]*a2w3 + KD[8]*a2w4 + off;
          float ae = fabsf(ve);
          acc += (ae < 1.f) ? 0.5f * ve * ve : ae - 0.5f;
          float ao = fabsf(vo);
          acc += (ao < 1.f) ? 0.5f * vo * vo : ao - 0.5f;
        }
      }
    }
  }
  return acc;
}

DEVI float wave_sum(float v) {
#pragma unroll
  for (int d = 32; d; d >>= 1) v += __shfl_down(v, d);
  return v;
}

DEVI float block_sum(float v, float* sh) {
  int lane = threadIdx.x & 63, wid = threadIdx.x >> 6;
  v = wave_sum(v);
  if (lane == 0) sh[wid] = v;
  __syncthreads();
  if (threadIdx.x == 0) {
    float s = 0.f;
    int nw = blockDim.x >> 6;
    for (int w = 0; w < nw; ++w) s += sh[w];
    sh[0] = s;
  }
  __syncthreads();
  float r = sh[0];
  __syncthreads();
  return r;
}

// inclusive suffix sum across 256 threads; sh must be int[256]
DEVI int suffix_scan_256(int v, int* sh) {
  int t = threadIdx.x;
  sh[t] = v;
  __syncthreads();
#pragma unroll
  for (int off = 1; off < 256; off <<= 1) {
    int x = (t + off < 256) ? sh[t + off] : 0;
    __syncthreads();
    sh[t] += x;
    __syncthreads();
  }
  return sh[t];
}

// Fused over 3 scales; per-block LDS 8-bit-exp CE histogram flushed as
// NON-ATOMIC per-block partials. blockIdx.y = axis.
__global__ void __launch_bounds__(256, 2)
pixel_kernel(const float* __restrict__ cls3, const float* __restrict__ reg3, const float* __restrict__ gt3,
             const float* __restrict__ cls4, const float* __restrict__ reg4, const float* __restrict__ gt4,
             const float* __restrict__ cls5, const float* __restrict__ reg5, const float* __restrict__ gt5,
             float* __restrict__ ws) {
  int bx = blockIdx.x, axis = blockIdx.y;
  const float *cls, *reg, *gt;
  int M, HW, ceOff, partBase, phRel, nb, lbx;
  if (bx < NB3) {
    cls = cls3; reg = reg3; gt = gt3; M = 80000; HW = 10000;
    ceOff = 0; partBase = PART_OFF; phRel = 0; nb = NB3; lbx = bx;
  } else if (bx < NB3 + NB4) {
    cls = cls4; reg = reg4; gt = gt4; M = 20000; HW = 2500;
    ceOff = 80000; partBase = PART_OFF + PART_STRIDE; phRel = PH1_REL; nb = NB4; lbx = bx - NB3;
  } else {
    cls = cls5; reg = reg5; gt = gt5; M = 5000; HW = 625;
    ceOff = 100000; partBase = PART_OFF + 2 * PART_STRIDE; phRel = PH2_REL; nb = NB5; lbx = bx - NB3 - NB4;
  }
  float* ceArr = ws + ceOff;
  unsigned* ph = (unsigned*)(ws + PH_OFF) + phRel;

  __shared__ unsigned hlds[256];
  __shared__ float shp[4][6];
  hlds[threadIdx.x] = 0u;
  __syncthreads();

  int p = lbx * 256 + threadIdx.x;
  float cnt_pos = 0.f, cnt_neg = 0.f, s_ce_pos = 0.f, s_tcl_ttm = 0.f, s_tcl_negm = 0.f;
  float s_ttm_pp = 0.f;
  if (p < M) {
    int n = p / HW, hw = p % HW;
    const float* gb = gt  + (size_t)n * 45 * HW + hw;
    const float* rb = reg + (size_t)n * 42 * HW + hw;
    float tr = gb[0], train = gb[2*(size_t)HW];
    float ttm = tr * train;

    if (axis == 0) {
      const float* cb = cls + (size_t)n * 4 * HW + hw;
      float l0 = cb[0], l1 = cb[(size_t)HW], l2 = cb[2*(size_t)HW], l3 = cb[3*(size_t)HW];
      float tcl = gb[(size_t)HW];

      float m1 = fmaxf(l0, l1);
      float lse1 = m1 + __logf(__expf(l0 - m1) + __expf(l1 - m1));
      float ce_tr = lse1 - ((tr > 0.5f) ? l1 : l0);
      float m2 = fmaxf(l2, l3);
      float lse2 = m2 + __logf(__expf(l2 - m2) + __expf(l3 - m2));
      float ce_tcl = lse2 - ((tcl > 0.5f) ? l3 : l2);

      bool pos = ttm > 0.f;
      bool neg = ((1.f - tr) * train) > 0.f;
      float cev = neg ? ce_tr : 0.f;
      ceArr[p] = cev;
      if (neg) atomicAdd(&hlds[__float_as_uint(cev) >> 23], 1u);  // LDS-local

      cnt_pos = pos ? 1.f : 0.f;
      cnt_neg = neg ? 1.f : 0.f;
      s_ce_pos = pos ? ce_tr : 0.f;
      s_tcl_ttm = ce_tcl * ttm;
      s_tcl_negm = ce_tcl * (1.f - ttm);
    }

    int rc0 = (axis == 0) ? 0 : 21;
    int gc0 = (axis == 0) ? 3 : 24;
    float d[20];
#pragma unroll
    for (int c = 0; c < 20; ++c) d[c] = rb[(size_t)(rc0 + c) * HW] - gb[(size_t)(gc0 + c) * HW];
    float dc = rb[(size_t)(rc0 + 20) * HW] - gb[(size_t)(gc0 + 20) * HW];
    s_ttm_pp = ttm * recon_sl1(d, dc);
  }

  int lane = threadIdx.x & 63, wid = threadIdx.x >> 6;
  cnt_pos = wave_sum(cnt_pos);
  cnt_neg = wave_sum(cnt_neg);
  s_ce_pos = wave_sum(s_ce_pos);
  s_tcl_ttm = wave_sum(s_tcl_ttm);
  s_tcl_negm = wave_sum(s_tcl_negm);
  s_ttm_pp = wave_sum(s_ttm_pp);
  if (lane == 0) {
    shp[wid][0] = cnt_pos; shp[wid][1] = cnt_neg; shp[wid][2] = s_ce_pos;
    shp[wid][3] = s_tcl_ttm; shp[wid][4] = s_tcl_negm; shp[wid][5] = s_ttm_pp;
  }
  __syncthreads();
  if (threadIdx.x < 6) {
    float s = shp[0][threadIdx.x] + shp[1][threadIdx.x] + shp[2][threadIdx.x] + shp[3][threadIdx.x];
    ws[partBase + (size_t)(axis * nb + lbx) * 6 + threadIdx.x] = s;
  }
  if (axis == 0)
    ph[(size_t)lbx * 256 + threadIdx.x] = hlds[threadIdx.x];
}

// one block per scale: reduce partials -> acc; LINEAR uint4 sweep of exp-hist
// partials with LDS-atomic binning (pipelined, no strided latency chain);
// suffix-scan -> (ibin, rem). Also zeroes SUMGT/CCNT[s] and out (block 0).
__global__ void selA_kernel(float* __restrict__ ws, float* __restrict__ out) {
  int s = blockIdx.x, t = threadIdx.x;
  float* acc = ws + ACC_OFF + s * 8;
  int* st = (int*)(ws + STATE_OFF) + s * 8;
  int phRel = (s == 0) ? 0 : (s == 1 ? PH1_REL : PH2_REL);
  const unsigned* ph = (const unsigned*)(ws + PH_OFF) + phRel;
  const float* part = ws + PART_OFF + s * PART_STRIDE;
  int nb0 = (s == 0) ? NB3 : (s == 1 ? NB4 : NB5);
  int npart = 2 * nb0;

  __shared__ int sh[256];
  __shared__ int sel[2];
  __shared__ float red[4];
  __shared__ unsigned hbin[256];

  // re-init cross-kernel accumulators for this graph replay
  if (t == 0) {
    ws[SUMGT_OFF + s] = 0.f;
    ((unsigned*)(ws + CCNT_OFF))[s] = 0u;
    if (s == 0) { out[0] = 0.f; out[1] = 0.f; out[2] = 0.f; }
  }
  hbin[t] = 0u;

  float a0 = 0.f, a1 = 0.f, a2 = 0.f, a3 = 0.f, a4 = 0.f, a5 = 0.f;
  for (int i = t; i < npart; i += 256) {
    const float* p6 = part + (size_t)i * 6;
    a0 += p6[0]; a1 += p6[1]; a2 += p6[2]; a3 += p6[3]; a4 += p6[4]; a5 += p6[5];
  }
  a0 = block_sum(a0, red);
  a1 = block_sum(a1, red);
  a2 = block_sum(a2, red);
  a3 = block_sum(a3, red);
  a4 = block_sum(a4, red);
  a5 = block_sum(a5, red);
  if (t == 0) { acc[0] = a0; acc[1] = a1; acc[2] = a2; acc[3] = a3; acc[4] = a4; acc[5] = a5; }

  float cnt_pos = a0, cnt_negf = a1;
  int cnt_neg = (int)cnt_negf;
  float kf = (cnt_pos > 0.f) ? fminf(cnt_negf, floorf(3.f * cnt_pos)) : 100.f;
  int k_take = min((int)kf, cnt_neg);

  int ibin, rem;
  if (k_take >= cnt_neg) { ibin = -1; rem = 0; }        // take all negatives
  else if (k_take <= 0)  { ibin = 256; rem = 0; }       // take none
  else {
    // linear sweep: each wave's 64 uint4 lanes cover all 256 bins exactly once
    const uint4* ph4 = (const uint4*)ph;
    int n4 = nb0 * 64;
    for (int i = t; i < n4; i += 256) {
      uint4 u = ph4[i];
      int b0 = (i * 4) & 255;
      atomicAdd(&hbin[b0 + 0], u.x);
      atomicAdd(&hbin[b0 + 1], u.y);
      atomicAdd(&hbin[b0 + 2], u.z);
      atomicAdd(&hbin[b0 + 3], u.w);
    }
    __syncthreads();
    int h = (int)hbin[t];
    int suf = suffix_scan_256(h, sh);
    int above = suf - h;
    if (suf >= k_take && above < k_take) { sel[0] = t; sel[1] = k_take - above; }
    __syncthreads();
    ibin = sel[0]; rem = sel[1];
  }
  if (t == 0) {
    st[0] = ibin;
    st[1] = rem;
    ((float*)st)[2] = kf;
    st[3] = k_take;
  }
}

// grid-wide: sum ce with exp-bin > ibin into SUMGT (1 atomic/block);
// LDS hist of mantissa[22:15] for exp-bin == ibin -> per-block partials
__global__ void refine_kernel(float* __restrict__ ws) {
  int s = blockIdx.y;
  int M   = (s == 0) ? 80000 : (s == 1 ? 20000 : 5000);
  int off = (s == 0) ? 0     : (s == 1 ? 80000 : 100000);
  const int* st = (const int*)(ws + STATE_OFF) + s * 8;
  int ibin = st[0], rem = st[1];
  if (ibin >= 256) return;   // take-none

  __shared__ unsigned hlds[256];
  __shared__ float red[4];
  hlds[threadIdx.x] = 0u;
  __syncthreads();

  const float* ce = ws + off;
  int stride = gridDim.x * blockDim.x;
  float sum = 0.f;
  for (int i = blockIdx.x * blockDim.x + threadIdx.x; i < M; i += stride) {
    float v = ce[i];
    unsigned b = __float_as_uint(v);
    int bin = (int)(b >> 23);
    if (bin > ibin) sum += v;
    else if (bin == ibin && rem > 0) atomicAdd(&hlds[(b >> 15) & 255u], 1u);
  }
  sum = block_sum(sum, red);   // syncthreads inside also orders the LDS atomics
  if (threadIdx.x == 0 && sum != 0.f) atomicAdd(ws + SUMGT_OFF + s, sum);
  if (rem > 0) {
    unsigned* mh = (unsigned*)(ws + MH_OFF) + (size_t)s * MH_STRIDE;
    mh[(size_t)blockIdx.x * 256 + threadIdx.x] = hlds[threadIdx.x];
  }
}

// one block per scale: column-sum m8 partials (linear uint4 sweep) -> (jbin, rem2)
__global__ void selB_kernel(float* __restrict__ ws) {
  int s = blockIdx.x, t = threadIdx.x;
  int* st = (int*)(ws + STATE_OFF) + s * 8;
  int rem = st[1];

  __shared__ int sh[256];
  __shared__ int sel[2];
  __shared__ unsigned hbin[256];
  hbin[t] = 0u;

  int jbin = 0, rem2 = 0;
  if (rem > 0) {
    const uint4* mh4 = (const uint4*)((const unsigned*)(ws + MH_OFF) + (size_t)s * MH_STRIDE);
    int n4 = NBR * 64;
    __syncthreads();
    for (int i = t; i < n4; i += 256) {
      uint4 u = mh4[i];
      int b0 = (i * 4) & 255;
      atomicAdd(&hbin[b0 + 0], u.x);
      atomicAdd(&hbin[b0 + 1], u.y);
      atomicAdd(&hbin[b0 + 2], u.z);
      atomicAdd(&hbin[b0 + 3], u.w);
    }
    __syncthreads();
    int h = (int)hbin[t];
    int suf = suffix_scan_256(h, sh);
    int above = suf - h;
    if (suf >= rem && above < rem) { sel[0] = t; sel[1] = rem - above; }
    __syncthreads();
    jbin = sel[0]; rem2 = sel[1];
  }
  if (t == 0) { st[4] = jbin; st[5] = rem2; }
}

// grid-wide: sum (exp==ibin, m8>jbin) into SUMGT; two-phase compact of
// (ibin,jbin) matches into cbuf
__global__ void compact_kernel(float* __restrict__ ws) {
  int s = blockIdx.y;
  int M   = (s == 0) ? 80000 : (s == 1 ? 20000 : 5000);
  int off = (s == 0) ? 0     : (s == 1 ? 80000 : 100000);
  const int* st = (const int*)(ws + STATE_OFF) + s * 8;
  int ibin = st[0], rem = st[1], jbin = st[4];
  if (rem <= 0) return;

  __shared__ float red[4];
  __shared__ unsigned sbase;
  __shared__ unsigned wcnt;

  const float* ce = ws + off;
  float* cbuf = ws + CBUF_OFF + s * CAP;
  unsigned* ccnt = (unsigned*)(ws + CCNT_OFF) + s;
  int stride = gridDim.x * blockDim.x;
  int i0 = blockIdx.x * blockDim.x + threadIdx.x;

  float sum = 0.f, cin = 0.f;
  for (int i = i0; i < M; i += stride) {
    unsigned b = __float_as_uint(ce[i]);
    if ((int)(b >> 23) == ibin) {
      int m8 = (int)((b >> 15) & 255u);
      if (m8 > jbin) sum += ce[i];
      else if (m8 == jbin) cin += 1.f;
    }
  }
  sum = block_sum(sum, red);
  cin = block_sum(cin, red);
  if (threadIdx.x == 0) {
    if (sum != 0.f) atomicAdd(ws + SUMGT_OFF + s, sum);
    sbase = (cin > 0.f) ? atomicAdd(ccnt, (unsigned)cin) : 0u;
    wcnt = 0u;
  }
  __syncthreads();
  unsigned base = sbase;
  for (int i = i0; i < M; i += stride) {
    float v = ce[i];
    unsigned b = __float_as_uint(v);
    if ((int)(b >> 23) == ibin && (int)((b >> 15) & 255u) == jbin) {
      unsigned idx = base + atomicAdd(&wcnt, 1u);
      if (idx < CAP) cbuf[idx] = v;
    }
  }
}

// one block per scale: 2 radix passes (bits 14..7, 6..0) over the small cbuf
// -> exact k-th value; tie-corrected sum; assemble losses.
__global__ void final_kernel(float* __restrict__ ws, float* __restrict__ out) {
  int s = blockIdx.x, t = threadIdx.x;
  int M = (s == 0) ? 80000 : (s == 1 ? 20000 : 5000);
  const float* acc = ws + ACC_OFF + s * 8;
  const int* st = (const int*)(ws + STATE_OFF) + s * 8;

  __shared__ int hist[256];
  __shared__ int sh[256];
  __shared__ int sel[2];
  __shared__ float red[8];

  float cnt_pos = acc[0];
  float s_ce_pos = acc[2], s_tcl_ttm = acc[3], s_tcl_negm = acc[4], s_ttm_pp = acc[5];
  int ibin = st[0], jbin = st[4], rem2 = st[5];
  float kf = ((const float*)st)[2];
  float loss_neg = ws[SUMGT_OFF + s];

  if (rem2 > 0) {
    int cnt = min((int)((unsigned*)(ws + CCNT_OFF))[s], CAP);
    const float* cbuf = ws + CBUF_OFF + s * CAP;
    unsigned prefix = ((unsigned)ibin << 23) | ((unsigned)jbin << 15);
    int remcur = rem2;

    // pass 1: bits 14..7 (all cbuf values share the 17-bit prefix)
    hist[t] = 0; __syncthreads();
    for (int i = t; i < cnt; i += 256)
      atomicAdd(&hist[(__float_as_uint(cbuf[i]) >> 7) & 255u], 1);
    __syncthreads();
    int h = hist[t];
    int suf = suffix_scan_256(h, sh);
    int above = suf - h;
    if (suf >= remcur && above < remcur) { sel[0] = t; sel[1] = remcur - above; }
    __syncthreads();
    int b1 = sel[0]; remcur = sel[1];
    __syncthreads();

    // pass 2: bits 6..0 among values matching b1
    hist[t] = 0; __syncthreads();
    for (int i = t; i < cnt; i += 256) {
      unsigned b = __float_as_uint(cbuf[i]);
      if (((b >> 7) & 255u) == (unsigned)b1) atomicAdd(&hist[b & 127u], 1);
    }
    __syncthreads();
    h = (t < 128) ? hist[t] : 0;
    suf = suffix_scan_256(h, sh);
    above = suf - h;
    if (t < 128 && suf >= remcur && above < remcur) { sel[0] = t; }
    __syncthreads();
    int b0 = sel[0];
    __syncthreads();

    prefix |= ((unsigned)b1 << 7) | (unsigned)b0;
    float tval = __uint_as_float(prefix);

    float sum_in = 0.f, cgt = 0.f;
    for (int i = t; i < cnt; i += 256) {
      unsigned b = __float_as_uint(cbuf[i]);
      if (b > prefix) { sum_in += cbuf[i]; cgt += 1.f; }
    }
    sum_in = block_sum(sum_in, red);
    cgt = block_sum(cgt, red);
    loss_neg += sum_in + ((float)rem2 - cgt) * tval;
  }

  if (t == 0) {
    float n_pos = cnt_pos;
    float loss_pos = (n_pos > 0.f) ? s_ce_pos : 0.f;
    float loss_tr = (loss_pos + loss_neg) / (n_pos + kf);

    float negm = (float)M - n_pos;
    float mp = s_tcl_ttm / fmaxf(n_pos, 1.f);
    float mn = s_tcl_negm / fmaxf(negm, 1.f);
    float loss_tcl = (n_pos > 0.f) ? (mp + 0.5f * mn) : 0.f;

    float loss_ct = (n_pos > 0.f) ? (0.5f * s_ttm_pp / (n_pos * 200.f)) : 0.f;

    atomicAdd(&out[0], loss_tr);
    atomicAdd(&out[1], loss_tcl);
    atomicAdd(&out[2], loss_ct);
  }
}

extern "C" void kernel_launch(void* const* d_in, const int* in_sizes, int n_in,
                              void* d_out, int out_size, void* d_ws, size_t ws_size,
                              hipStream_t stream) {
  (void)in_sizes; (void)n_in; (void)out_size; (void)ws_size;
  const float* cls3 = (const float*)d_in[0];
  const float* reg3 = (const float*)d_in[1];
  const float* gt3  = (const float*)d_in[2];
  const float* cls4 = (const float*)d_in[3];
  const float* reg4 = (const float*)d_in[4];
  const float* gt4  = (const float*)d_in[5];
  const float* cls5 = (const float*)d_in[6];
  const float* reg5 = (const float*)d_in[7];
  const float* gt5  = (const float*)d_in[8];

  float* ws = (float*)d_ws;
  float* out = (float*)d_out;

  pixel_kernel<<<dim3(NB3 + NB4 + NB5, 2), 256, 0, stream>>>(
      cls3, reg3, gt3, cls4, reg4, gt4, cls5, reg5, gt5, ws);

  selA_kernel<<<3, 256, 0, stream>>>(ws, out);
  refine_kernel<<<dim3(NBR, 3), 256, 0, stream>>>(ws);
  selB_kernel<<<3, 256, 0, stream>>>(ws);
  compact_kernel<<<dim3(NBR, 3), 256, 0, stream>>>(ws);
  final_kernel<<<3, 256, 0, stream>>>(ws, out);
}

// Round 11
// 78.381 us; speedup vs baseline: 1.7034x; 1.0087x over previous
//
#include <hip/hip_runtime.h>
#include <math.h>

#define DEVI __device__ __forceinline__

static constexpr float KD[10] = {
  0.027333068345077982f,  0.029519490925774643f, -0.039134249302383094f,
  0.1993975339773936f,    0.7234076904024206f,    0.6339789634582119f,
  0.01660210576452232f,  -0.17532808990845047f,  -0.021101834024758855f,
  0.019538882735286728f};

// ---------- workspace layout (float offsets) ----------
#define CE_OFF     0         // 105000 floats (ce per pixel, 0 for non-negatives)
#define ACC_OFF    105000    // 3 x 8 floats
#define SUMGT_OFF  105024    // 3 floats
#define CCNT_OFF   105027    // 3 uints
#define STATE_OFF  105030    // 3 x 8 words: [0]=ibin [1]=rem [2]=kf [3]=k_take [4]=jbin [5]=rem2
#define PH_OFF     105056    // exp-hist partials: NBs x 256 uints per scale (16B-aligned)
#define PH1_REL    80128     // NB3*256
#define PH2_REL    100352    // + NB4*256
#define MH_OFF     210528    // m8-hist partials: 3 x 96 x 256 uints
#define MH_STRIDE  24576
#define CBUF_OFF   284256    // 3 x CAP floats
#define CAP        61440
#define PART_OFF   468576    // 3 x PART_STRIDE floats (per-block partials)
#define PART_STRIDE 7680     // >= 4*NB3*6 = 7512

#define NB3 313
#define NB4 79
#define NB5 20
#define NBR 96               // refine/compact grid.x

DEVI float wave_sum(float v) {
#pragma unroll
  for (int d = 32; d; d >>= 1) v += __shfl_down(v, d);
  return v;
}

DEVI float block_sum(float v, float* sh) {
  int lane = threadIdx.x & 63, wid = threadIdx.x >> 6;
  v = wave_sum(v);
  if (lane == 0) sh[wid] = v;
  __syncthreads();
  if (threadIdx.x == 0) {
    float s = 0.f;
    int nw = blockDim.x >> 6;
    for (int w = 0; w < nw; ++w) s += sh[w];
    sh[0] = s;
  }
  __syncthreads();
  float r = sh[0];
  __syncthreads();
  return r;
}

// inclusive suffix sum across 256 threads; sh must be int[256]
DEVI int suffix_scan_256(int v, int* sh) {
  int t = threadIdx.x;
  sh[t] = v;
  __syncthreads();
#pragma unroll
  for (int off = 1; off < 256; off <<= 1) {
    int x = (t + off < 256) ? sh[t + off] : 0;
    __syncthreads();
    sh[t] += x;
    __syncthreads();
  }
  return sh[t];
}

// HALF of waverec3+smooth_l1: outputs [50h, 50h+50). Dependency cone:
//  H=0: a2[0..28] <- a1[0..18] <- c[0..13]
//  H=1: a2[25..53] <- a1[12..30] <- c[6..19]
// All indices compile-time (template) -> registers, no scratch.
template <int H>
DEVI float recon_sl1_half(const float* __restrict__ rb, const float* __restrict__ gb,
                          int rc0, int gc0, size_t HW, float off) {
  constexpr int CLO  = (H == 0) ? 0 : 6;    // c window base (14 coeffs)
  constexpr int A1LO = (H == 0) ? 0 : 12;   // a1 indices [A1LO, A1LO+19)
  constexpr int J2LO = (H == 0) ? 0 : 25;   // a2 indices [J2LO, J2LO+29)

  float c[14];
#pragma unroll
  for (int i = 0; i < 14; ++i)
    c[i] = rb[(size_t)(rc0 + CLO + i) * HW] - gb[(size_t)(gc0 + CLO + i) * HW];

  float a1[19];
#pragma unroll
  for (int k = 0; k < 19; ++k) {
    constexpr int base = A1LO;
    int o1 = base + k;
    int b = (o1 >> 1) - CLO;
    if (o1 & 1)
      a1[k] = KD[0]*c[b] + KD[2]*c[b+1] + KD[4]*c[b+2] + KD[6]*c[b+3] + KD[8]*c[b+4];
    else
      a1[k] = KD[1]*c[b] + KD[3]*c[b+1] + KD[5]*c[b+2] + KD[7]*c[b+3] + KD[9]*c[b+4];
  }

  float w0 = 0.f, w1 = 0.f, w2 = 0.f, w3 = 0.f, w4 = 0.f;
  float acc = 0.f;
#pragma unroll
  for (int k = 0; k < 29; ++k) {
    int j2 = J2LO + k;
    int b = (j2 >> 1) - A1LO;
    float a2v;
    if (j2 & 1)
      a2v = KD[0]*a1[b] + KD[2]*a1[b+1] + KD[4]*a1[b+2] + KD[6]*a1[b+3] + KD[8]*a1[b+4];
    else
      a2v = KD[1]*a1[b] + KD[3]*a1[b+1] + KD[5]*a1[b+2] + KD[7]*a1[b+3] + KD[9]*a1[b+4];
    w0 = w1; w1 = w2; w2 = w3; w3 = w4; w4 = a2v;
    if (k >= 4) {
      float ve = KD[1]*w0 + KD[3]*w1 + KD[5]*w2 + KD[7]*w3 + KD[9]*w4 + off;
      float vo = KD[0]*w0 + KD[2]*w1 + KD[4]*w2 + KD[6]*w3 + KD[8]*w4 + off;
      float ae = fabsf(ve);
      acc += (ae < 1.f) ? 0.5f * ve * ve : ae - 0.5f;
      float ao = fabsf(vo);
      acc += (ao < 1.f) ? 0.5f * vo * vo : ao - 0.5f;
    }
  }
  return acc;
}

// Fused over 3 scales; blockIdx.y in [0,4): axis = y>>1, half = y&1.
// CE/mask/hist work only in y==0 blocks. Per-block LDS exp-hist flushed as
// NON-ATOMIC per-block partials.
__global__ void __launch_bounds__(256, 2)
pixel_kernel(const float* __restrict__ cls3, const float* __restrict__ reg3, const float* __restrict__ gt3,
             const float* __restrict__ cls4, const float* __restrict__ reg4, const float* __restrict__ gt4,
             const float* __restrict__ cls5, const float* __restrict__ reg5, const float* __restrict__ gt5,
             float* __restrict__ ws) {
  int bx = blockIdx.x, y = blockIdx.y;
  int axis = y >> 1, half = y & 1;
  const float *cls, *reg, *gt;
  int M, HW, ceOff, partBase, phRel, nb, lbx;
  if (bx < NB3) {
    cls = cls3; reg = reg3; gt = gt3; M = 80000; HW = 10000;
    ceOff = 0; partBase = PART_OFF; phRel = 0; nb = NB3; lbx = bx;
  } else if (bx < NB3 + NB4) {
    cls = cls4; reg = reg4; gt = gt4; M = 20000; HW = 2500;
    ceOff = 80000; partBase = PART_OFF + PART_STRIDE; phRel = PH1_REL; nb = NB4; lbx = bx - NB3;
  } else {
    cls = cls5; reg = reg5; gt = gt5; M = 5000; HW = 625;
    ceOff = 100000; partBase = PART_OFF + 2 * PART_STRIDE; phRel = PH2_REL; nb = NB5; lbx = bx - NB3 - NB4;
  }
  float* ceArr = ws + ceOff;
  unsigned* ph = (unsigned*)(ws + PH_OFF) + phRel;

  __shared__ unsigned hlds[256];
  __shared__ float shp[4][6];
  hlds[threadIdx.x] = 0u;
  __syncthreads();

  int p = lbx * 256 + threadIdx.x;
  float cnt_pos = 0.f, cnt_neg = 0.f, s_ce_pos = 0.f, s_tcl_ttm = 0.f, s_tcl_negm = 0.f;
  float s_ttm_pp = 0.f;
  if (p < M) {
    int n = p / HW, hw = p % HW;
    const float* gb = gt  + (size_t)n * 45 * HW + hw;
    const float* rb = reg + (size_t)n * 42 * HW + hw;
    float tr = gb[0], train = gb[2*(size_t)HW];
    float ttm = tr * train;

    if (y == 0) {
      const float* cb = cls + (size_t)n * 4 * HW + hw;
      float l0 = cb[0], l1 = cb[(size_t)HW], l2 = cb[2*(size_t)HW], l3 = cb[3*(size_t)HW];
      float tcl = gb[(size_t)HW];

      float m1 = fmaxf(l0, l1);
      float lse1 = m1 + __logf(__expf(l0 - m1) + __expf(l1 - m1));
      float ce_tr = lse1 - ((tr > 0.5f) ? l1 : l0);
      float m2 = fmaxf(l2, l3);
      float lse2 = m2 + __logf(__expf(l2 - m2) + __expf(l3 - m2));
      float ce_tcl = lse2 - ((tcl > 0.5f) ? l3 : l2);

      bool pos = ttm > 0.f;
      bool neg = ((1.f - tr) * train) > 0.f;
      float cev = neg ? ce_tr : 0.f;
      ceArr[p] = cev;
      if (neg) atomicAdd(&hlds[__float_as_uint(cev) >> 23], 1u);  // LDS-local

      cnt_pos = pos ? 1.f : 0.f;
      cnt_neg = neg ? 1.f : 0.f;
      s_ce_pos = pos ? ce_tr : 0.f;
      s_tcl_ttm = ce_tcl * ttm;
      s_tcl_negm = ce_tcl * (1.f - ttm);
    }

    int rc0 = axis ? 21 : 0;
    int gc0 = axis ? 24 : 3;
    float dc = rb[(size_t)(rc0 + 20) * HW] - gb[(size_t)(gc0 + 20) * HW];
    float pp = half ? recon_sl1_half<1>(rb, gb, rc0, gc0, (size_t)HW, dc)
                    : recon_sl1_half<0>(rb, gb, rc0, gc0, (size_t)HW, dc);
    s_ttm_pp = ttm * pp;
  }

  int lane = threadIdx.x & 63, wid = threadIdx.x >> 6;
  cnt_pos = wave_sum(cnt_pos);
  cnt_neg = wave_sum(cnt_neg);
  s_ce_pos = wave_sum(s_ce_pos);
  s_tcl_ttm = wave_sum(s_tcl_ttm);
  s_tcl_negm = wave_sum(s_tcl_negm);
  s_ttm_pp = wave_sum(s_ttm_pp);
  if (lane == 0) {
    shp[wid][0] = cnt_pos; shp[wid][1] = cnt_neg; shp[wid][2] = s_ce_pos;
    shp[wid][3] = s_tcl_ttm; shp[wid][4] = s_tcl_negm; shp[wid][5] = s_ttm_pp;
  }
  __syncthreads();
  if (threadIdx.x < 6) {
    float s = shp[0][threadIdx.x] + shp[1][threadIdx.x] + shp[2][threadIdx.x] + shp[3][threadIdx.x];
    ws[partBase + (size_t)(y * nb + lbx) * 6 + threadIdx.x] = s;
  }
  if (y == 0)
    ph[(size_t)lbx * 256 + threadIdx.x] = hlds[threadIdx.x];
}

// one block per scale: reduce partials -> acc; LINEAR uint4 sweep of exp-hist
// partials with LDS-atomic binning; suffix-scan -> (ibin, rem).
// Also zeroes SUMGT/CCNT[s] and out (block 0).
__global__ void selA_kernel(float* __restrict__ ws, float* __restrict__ out) {
  int s = blockIdx.x, t = threadIdx.x;
  float* acc = ws + ACC_OFF + s * 8;
  int* st = (int*)(ws + STATE_OFF) + s * 8;
  int phRel = (s == 0) ? 0 : (s == 1 ? PH1_REL : PH2_REL);
  const unsigned* ph = (const unsigned*)(ws + PH_OFF) + phRel;
  const float* part = ws + PART_OFF + s * PART_STRIDE;
  int nb0 = (s == 0) ? NB3 : (s == 1 ? NB4 : NB5);
  int npart = 4 * nb0;

  __shared__ int sh[256];
  __shared__ int sel[2];
  __shared__ float red[4];
  __shared__ unsigned hbin[256];

  if (t == 0) {
    ws[SUMGT_OFF + s] = 0.f;
    ((unsigned*)(ws + CCNT_OFF))[s] = 0u;
    if (s == 0) { out[0] = 0.f; out[1] = 0.f; out[2] = 0.f; }
  }
  hbin[t] = 0u;

  float a0 = 0.f, a1 = 0.f, a2 = 0.f, a3 = 0.f, a4 = 0.f, a5 = 0.f;
  for (int i = t; i < npart; i += 256) {
    const float* p6 = part + (size_t)i * 6;
    a0 += p6[0]; a1 += p6[1]; a2 += p6[2]; a3 += p6[3]; a4 += p6[4]; a5 += p6[5];
  }
  a0 = block_sum(a0, red);
  a1 = block_sum(a1, red);
  a2 = block_sum(a2, red);
  a3 = block_sum(a3, red);
  a4 = block_sum(a4, red);
  a5 = block_sum(a5, red);
  if (t == 0) { acc[0] = a0; acc[1] = a1; acc[2] = a2; acc[3] = a3; acc[4] = a4; acc[5] = a5; }

  float cnt_pos = a0, cnt_negf = a1;
  int cnt_neg = (int)cnt_negf;
  float kf = (cnt_pos > 0.f) ? fminf(cnt_negf, floorf(3.f * cnt_pos)) : 100.f;
  int k_take = min((int)kf, cnt_neg);

  int ibin, rem;
  if (k_take >= cnt_neg) { ibin = -1; rem = 0; }        // take all negatives
  else if (k_take <= 0)  { ibin = 256; rem = 0; }       // take none
  else {
    const uint4* ph4 = (const uint4*)ph;
    int n4 = nb0 * 64;
    for (int i = t; i < n4; i += 256) {
      uint4 u = ph4[i];
      int b0 = (i * 4) & 255;
      atomicAdd(&hbin[b0 + 0], u.x);
      atomicAdd(&hbin[b0 + 1], u.y);
      atomicAdd(&hbin[b0 + 2], u.z);
      atomicAdd(&hbin[b0 + 3], u.w);
    }
    __syncthreads();
    int h = (int)hbin[t];
    int suf = suffix_scan_256(h, sh);
    int above = suf - h;
    if (suf >= k_take && above < k_take) { sel[0] = t; sel[1] = k_take - above; }
    __syncthreads();
    ibin = sel[0]; rem = sel[1];
  }
  if (t == 0) {
    st[0] = ibin;
    st[1] = rem;
    ((float*)st)[2] = kf;
    st[3] = k_take;
  }
}

// grid-wide: sum ce with exp-bin > ibin into SUMGT (1 atomic/block);
// LDS hist of mantissa[22:15] for exp-bin == ibin -> per-block partials
__global__ void refine_kernel(float* __restrict__ ws) {
  int s = blockIdx.y;
  int M   = (s == 0) ? 80000 : (s == 1 ? 20000 : 5000);
  int off = (s == 0) ? 0     : (s == 1 ? 80000 : 100000);
  const int* st = (const int*)(ws + STATE_OFF) + s * 8;
  int ibin = st[0], rem = st[1];
  if (ibin >= 256) return;   // take-none

  __shared__ unsigned hlds[256];
  __shared__ float red[4];
  hlds[threadIdx.x] = 0u;
  __syncthreads();

  const float* ce = ws + off;
  int stride = gridDim.x * blockDim.x;
  float sum = 0.f;
  for (int i = blockIdx.x * blockDim.x + threadIdx.x; i < M; i += stride) {
    float v = ce[i];
    unsigned b = __float_as_uint(v);
    int bin = (int)(b >> 23);
    if (bin > ibin) sum += v;
    else if (bin == ibin && rem > 0) atomicAdd(&hlds[(b >> 15) & 255u], 1u);
  }
  sum = block_sum(sum, red);   // syncthreads inside also orders the LDS atomics
  if (threadIdx.x == 0 && sum != 0.f) atomicAdd(ws + SUMGT_OFF + s, sum);
  if (rem > 0) {
    unsigned* mh = (unsigned*)(ws + MH_OFF) + (size_t)s * MH_STRIDE;
    mh[(size_t)blockIdx.x * 256 + threadIdx.x] = hlds[threadIdx.x];
  }
}

// one block per scale: column-sum m8 partials (linear uint4 sweep) -> (jbin, rem2)
__global__ void selB_kernel(float* __restrict__ ws) {
  int s = blockIdx.x, t = threadIdx.x;
  int* st = (int*)(ws + STATE_OFF) + s * 8;
  int rem = st[1];

  __shared__ int sh[256];
  __shared__ int sel[2];
  __shared__ unsigned hbin[256];
  hbin[t] = 0u;

  int jbin = 0, rem2 = 0;
  if (rem > 0) {
    const uint4* mh4 = (const uint4*)((const unsigned*)(ws + MH_OFF) + (size_t)s * MH_STRIDE);
    int n4 = NBR * 64;
    __syncthreads();
    for (int i = t; i < n4; i += 256) {
      uint4 u = mh4[i];
      int b0 = (i * 4) & 255;
      atomicAdd(&hbin[b0 + 0], u.x);
      atomicAdd(&hbin[b0 + 1], u.y);
      atomicAdd(&hbin[b0 + 2], u.z);
      atomicAdd(&hbin[b0 + 3], u.w);
    }
    __syncthreads();
    int h = (int)hbin[t];
    int suf = suffix_scan_256(h, sh);
    int above = suf - h;
    if (suf >= rem && above < rem) { sel[0] = t; sel[1] = rem - above; }
    __syncthreads();
    jbin = sel[0]; rem2 = sel[1];
  }
  if (t == 0) { st[4] = jbin; st[5] = rem2; }
}

// grid-wide: sum (exp==ibin, m8>jbin) into SUMGT; two-phase compact of
// (ibin,jbin) matches into cbuf
__global__ void compact_kernel(float* __restrict__ ws) {
  int s = blockIdx.y;
  int M   = (s == 0) ? 80000 : (s == 1 ? 20000 : 5000);
  int off = (s == 0) ? 0     : (s == 1 ? 80000 : 100000);
  const int* st = (const int*)(ws + STATE_OFF) + s * 8;
  int ibin = st[0], rem = st[1], jbin = st[4];
  if (rem <= 0) return;

  __shared__ float red[4];
  __shared__ unsigned sbase;
  __shared__ unsigned wcnt;

  const float* ce = ws + off;
  float* cbuf = ws + CBUF_OFF + s * CAP;
  unsigned* ccnt = (unsigned*)(ws + CCNT_OFF) + s;
  int stride = gridDim.x * blockDim.x;
  int i0 = blockIdx.x * blockDim.x + threadIdx.x;

  float sum = 0.f, cin = 0.f;
  for (int i = i0; i < M; i += stride) {
    unsigned b = __float_as_uint(ce[i]);
    if ((int)(b >> 23) == ibin) {
      int m8 = (int)((b >> 15) & 255u);
      if (m8 > jbin) sum += ce[i];
      else if (m8 == jbin) cin += 1.f;
    }
  }
  sum = block_sum(sum, red);
  cin = block_sum(cin, red);
  if (threadIdx.x == 0) {
    if (sum != 0.f) atomicAdd(ws + SUMGT_OFF + s, sum);
    sbase = (cin > 0.f) ? atomicAdd(ccnt, (unsigned)cin) : 0u;
    wcnt = 0u;
  }
  __syncthreads();
  unsigned base = sbase;
  for (int i = i0; i < M; i += stride) {
    float v = ce[i];
    unsigned b = __float_as_uint(v);
    if ((int)(b >> 23) == ibin && (int)((b >> 15) & 255u) == jbin) {
      unsigned idx = base + atomicAdd(&wcnt, 1u);
      if (idx < CAP) cbuf[idx] = v;
    }
  }
}

// one block per scale: 2 radix passes (bits 14..7, 6..0) over the small cbuf
// -> exact k-th value; tie-corrected sum; assemble losses.
__global__ void final_kernel(float* __restrict__ ws, float* __restrict__ out) {
  int s = blockIdx.x, t = threadIdx.x;
  int M = (s == 0) ? 80000 : (s == 1 ? 20000 : 5000);
  const float* acc = ws + ACC_OFF + s * 8;
  const int* st = (const int*)(ws + STATE_OFF) + s * 8;

  __shared__ int hist[256];
  __shared__ int sh[256];
  __shared__ int sel[2];
  __shared__ float red[8];

  float cnt_pos = acc[0];
  float s_ce_pos = acc[2], s_tcl_ttm = acc[3], s_tcl_negm = acc[4], s_ttm_pp = acc[5];
  int ibin = st[0], jbin = st[4], rem2 = st[5];
  float kf = ((const float*)st)[2];
  float loss_neg = ws[SUMGT_OFF + s];

  if (rem2 > 0) {
    int cnt = min((int)((unsigned*)(ws + CCNT_OFF))[s], CAP);
    const float* cbuf = ws + CBUF_OFF + s * CAP;
    unsigned prefix = ((unsigned)ibin << 23) | ((unsigned)jbin << 15);
    int remcur = rem2;

    // pass 1: bits 14..7 (all cbuf values share the 17-bit prefix)
    hist[t] = 0; __syncthreads();
    for (int i = t; i < cnt; i += 256)
      atomicAdd(&hist[(__float_as_uint(cbuf[i]) >> 7) & 255u], 1);
    __syncthreads();
    int h = hist[t];
    int suf = suffix_scan_256(h, sh);
    int above = suf - h;
    if (suf >= remcur && above < remcur) { sel[0] = t; sel[1] = remcur - above; }
    __syncthreads();
    int b1 = sel[0]; remcur = sel[1];
    __syncthreads();

    // pass 2: bits 6..0 among values matching b1
    hist[t] = 0; __syncthreads();
    for (int i = t; i < cnt; i += 256) {
      unsigned b = __float_as_uint(cbuf[i]);
      if (((b >> 7) & 255u) == (unsigned)b1) atomicAdd(&hist[b & 127u], 1);
    }
    __syncthreads();
    h = (t < 128) ? hist[t] : 0;
    suf = suffix_scan_256(h, sh);
    above = suf - h;
    if (t < 128 && suf >= remcur && above < remcur) { sel[0] = t; }
    __syncthreads();
    int b0 = sel[0];
    __syncthreads();

    prefix |= ((unsigned)b1 << 7) | (unsigned)b0;
    float tval = __uint_as_float(prefix);

    float sum_in = 0.f, cgt = 0.f;
    for (int i = t; i < cnt; i += 256) {
      unsigned b = __float_as_uint(cbuf[i]);
      if (b > prefix) { sum_in += cbuf[i]; cgt += 1.f; }
    }
    sum_in = block_sum(sum_in, red);
    cgt = block_sum(cgt, red);
    loss_neg += sum_in + ((float)rem2 - cgt) * tval;
  }

  if (t == 0) {
    float n_pos = cnt_pos;
    float loss_pos = (n_pos > 0.f) ? s_ce_pos : 0.f;
    float loss_tr = (loss_pos + loss_neg) / (n_pos + kf);

    float negm = (float)M - n_pos;
    float mp = s_tcl_ttm / fmaxf(n_pos, 1.f);
    float mn = s_tcl_negm / fmaxf(negm, 1.f);
    float loss_tcl = (n_pos > 0.f) ? (mp + 0.5f * mn) : 0.f;

    float loss_ct = (n_pos > 0.f) ? (0.5f * s_ttm_pp / (n_pos * 200.f)) : 0.f;

    atomicAdd(&out[0], loss_tr);
    atomicAdd(&out[1], loss_tcl);
    atomicAdd(&out[2], loss_ct);
  }
}

extern "C" void kernel_launch(void* const* d_in, const int* in_sizes, int n_in,
                              void* d_out, int out_size, void* d_ws, size_t ws_size,
                              hipStream_t stream) {
  (void)in_sizes; (void)n_in; (void)out_size; (void)ws_size;
  const float* cls3 = (const float*)d_in[0];
  const float* reg3 = (const float*)d_in[1];
  const float* gt3  = (const float*)d_in[2];
  const float* cls4 = (const float*)d_in[3];
  const float* reg4 = (const float*)d_in[4];
  const float* gt4  = (const float*)d_in[5];
  const float* cls5 = (const float*)d_in[6];
  const float* reg5 = (const float*)d_in[7];
  const float* gt5  = (const float*)d_in[8];

  float* ws = (float*)d_ws;
  float* out = (float*)d_out;

  pixel_kernel<<<dim3(NB3 + NB4 + NB5, 4), 256, 0, stream>>>(
      cls3, reg3, gt3, cls4, reg4, gt4, cls5, reg5, gt5, ws);

  selA_kernel<<<3, 256, 0, stream>>>(ws, out);
  refine_kernel<<<dim3(NBR, 3), 256, 0, stream>>>(ws);
  selB_kernel<<<3, 256, 0, stream>>>(ws);
  compact_kernel<<<dim3(NBR, 3), 256, 0, stream>>>(ws);
  final_kernel<<<3, 256, 0, stream>>>(ws, out);
}